// Round 13
// baseline (1685.561 us; speedup 1.0000x reference)
//
#include <hip/hip_runtime.h>
#include <math.h>

#define SEQT 2048
#define BATCH 256
#define INDIM 64
#define HDIM 128

typedef float v2f __attribute__((ext_vector_type(2)));
typedef _Float16 f16x2 __attribute__((ext_vector_type(2)));

// ---- fast branch-free erf (Abramowitz-Stegun 7.1.26, |abs err| <= 1.5e-7) ----
__device__ __forceinline__ float gelu_fast(float x) {
    const float ax = __builtin_fabsf(x);
    const float z  = ax * 0.70710678118654752f;
    const float t  = __builtin_amdgcn_rcpf(__builtin_fmaf(0.3275911f, z, 1.0f));
    float p = __builtin_fmaf(1.061405429f, t, -1.453152027f);
    p = __builtin_fmaf(p, t, 1.421413741f);
    p = __builtin_fmaf(p, t, -0.284496736f);
    p = __builtin_fmaf(p, t, 0.254829592f);
    p = p * t;
    const float e = __builtin_amdgcn_exp2f(z * z * -1.44269504088896f);
    const float erfv = __builtin_fmaf(-p, e, 1.0f);
    return __builtin_fmaf(0.5f * ax, erfv, 0.5f * x);
}

// f16 dot2 with f32 accumulate (v_dot2_f32_f16)
__device__ __forceinline__ float fdot2(f16x2 a, f16x2 b, float c) {
#if __has_builtin(__builtin_amdgcn_fdot2)
    return __builtin_amdgcn_fdot2(a, b, c, false);
#else
    asm("v_dot2_f32_f16 %0, %1, %2, %0" : "+v"(c) : "v"(a), "v"(b));
    return c;
#endif
}

__device__ __forceinline__ f16x2 bc16(unsigned u) { return __builtin_bit_cast(f16x2, u); }
__device__ __forceinline__ f16x2 cvt_pk(float x, float y) {
    return __builtin_bit_cast(f16x2, __builtin_amdgcn_cvt_pkrtz(x, y));
}
__device__ __forceinline__ unsigned cvt_pk_u(float x, float y) {
    return __builtin_bit_cast(unsigned, __builtin_amdgcn_cvt_pkrtz(x, y));
}

// LDS-only barrier: drain lgkmcnt (ds_write visibility) but NOT vmcnt —
// __syncthreads() would emit s_waitcnt vmcnt(0) before s_barrier, forcing the
// per-step y1 global_store and the x prefetch load to COMPLETE inside every
// step (~1000 cyc of HBM latency serialized into the scan). Global ops need
// no cross-wave ordering here: stores order at kernel end; prefetch loads are
// consumed by their own wave via compiler-inserted vmcnt waits.
__device__ __forceinline__ void bar_lds() {
    asm volatile("s_waitcnt lgkmcnt(0)\n\ts_barrier" ::: "memory");
}

// One workgroup per batch row. 256 threads = 4 waves, 1/SIMD, 1 barrier/step.
// Each wave owns ONE FULL matvec; lane l owns outputs 2l, 2l+1.
// Weights: f16-packed pairs wa[64] (row 2l), wb[64] (row 2l+1) = 128 VGPRs.
//   wv0 rec0  s=t-2: h0[s]=gelu(Wh0@h0[s-1]+xin0[s]); h via OWN-WAVE readlane
//   wv1 rec1  r=t-4: h1[r]=gelu(Wh1@h1[r-1]+xin1[r]); streams y1
//   wv2 xin1  u=t-3: Win1 @ h0[u] from packed-f16 LDS ring
//   wv3 xin0  τ=t  : Win0 @ x[τ]; stages x (lag-3 global prefetch)
// All rings depth-4; weight init = complete static per-role unrolls (SROA).
__global__ __launch_bounds__(256)
void rnn_scan_kernel(
    const float* __restrict__ seq,
    const float* __restrict__ Win0, const float* __restrict__ Wh0,
    const float* __restrict__ Win1, const float* __restrict__ Wh1,
    const float* __restrict__ h00, const float* __restrict__ h01,
    float* __restrict__ out)
{
    const int b = blockIdx.x;
    const int tid = threadIdx.x;
    const int wv = tid >> 6;
    const int l = tid & 63;

    __shared__ __align__(16) unsigned h0f16[4][64];   // packed-f16 h0 ring (for xin1)
    __shared__ __align__(16) v2f p1ring[4][64];       // xin1 results (per-lane)
    __shared__ __align__(16) v2f x0ring[4][64];       // xin0 results (per-lane)
    __shared__ __align__(16) float xring[4][INDIM];   // staged x (uniform-read)

    // ---- weights: rows 2l, 2l+1 as f16 pairs; complete static per-role loads ----
    f16x2 wa[64], wb[64];
    if (wv == 0 || wv == 1) {
        const float* W = (wv == 0) ? Wh0 : Wh1;
        const float* ra = &W[(2 * l) * HDIM];
        const float* rb = &W[(2 * l + 1) * HDIM];
        #pragma unroll
        for (int i = 0; i < 32; ++i) {
            float4 a = reinterpret_cast<const float4*>(ra)[i];
            float4 q = reinterpret_cast<const float4*>(rb)[i];
            wa[2 * i]     = cvt_pk(a.x, a.y);
            wa[2 * i + 1] = cvt_pk(a.z, a.w);
            wb[2 * i]     = cvt_pk(q.x, q.y);
            wb[2 * i + 1] = cvt_pk(q.z, q.w);
        }
    } else if (wv == 2) {
        const float* ra = &Win1[(2 * l) * HDIM];
        const float* rb = &Win1[(2 * l + 1) * HDIM];
        #pragma unroll
        for (int i = 0; i < 32; ++i) {
            float4 a = reinterpret_cast<const float4*>(ra)[i];
            float4 q = reinterpret_cast<const float4*>(rb)[i];
            wa[2 * i]     = cvt_pk(a.x, a.y);
            wa[2 * i + 1] = cvt_pk(a.z, a.w);
            wb[2 * i]     = cvt_pk(q.x, q.y);
            wb[2 * i + 1] = cvt_pk(q.z, q.w);
        }
    } else {
        const float* ra = &Win0[(2 * l) * INDIM];
        const float* rb = &Win0[(2 * l + 1) * INDIM];
        #pragma unroll
        for (int i = 0; i < 16; ++i) {
            float4 a = reinterpret_cast<const float4*>(ra)[i];
            float4 q = reinterpret_cast<const float4*>(rb)[i];
            wa[2 * i]     = cvt_pk(a.x, a.y);
            wa[2 * i + 1] = cvt_pk(a.z, a.w);
            wb[2 * i]     = cvt_pk(q.x, q.y);
            wb[2 * i + 1] = cvt_pk(q.z, q.w);
        }
        #pragma unroll
        for (int i = 32; i < 64; ++i) { wa[i] = (f16x2){0, 0}; wb[i] = (f16x2){0, 0}; }
    }

    // ---- init: recurrent state packed in-register; x staging (depth 3) ----
    unsigned hp_u = 0;            // lane's packed {h[2l], h[2l+1]} (rec waves)
    v2f hf = {0.f, 0.f};          // f32 copy of lane's h pair (for stores)
    float xA = 0.f, xB = 0.f, xC = 0.f;
    if (wv == 0) {
        hf = *reinterpret_cast<const v2f*>(&h00[2 * l]);
        hp_u = cvt_pk_u(hf.x, hf.y);
    } else if (wv == 1) {
        hf = *reinterpret_cast<const v2f*>(&h01[2 * l]);
        hp_u = cvt_pk_u(hf.x, hf.y);
    } else if (wv == 3) {
        const size_t base = (size_t)b * INDIM + l;
        xring[0][l] = seq[base];
        xring[1][l] = seq[(size_t)1 * BATCH * INDIM + base];
        xA          = seq[(size_t)2 * BATCH * INDIM + base];
        xB          = seq[(size_t)3 * BATCH * INDIM + base];
        xC          = seq[(size_t)4 * BATCH * INDIM + base];
    }
    __syncthreads();

    const size_t YSZ = (size_t)SEQT * BATCH * HDIM;

    for (int t = 0; t <= SEQT + 3; ++t) {
        if (wv == 0 || wv == 1) {
            // ---- rec: wv0 s=t-2 (h0), wv1 r=t-4 (h1) ----
            const int s = (wv == 0) ? (t - 2) : (t - 4);
            if (s >= 0 && s <= SEQT - 1) {
                // dot over K=128 via own-wave readlane of packed pairs
                float a0 = 0.f, a1 = 0.f, b0 = 0.f, b1 = 0.f;
                #pragma unroll
                for (int j = 0; j < 64; j += 2) {
                    unsigned s0 = __builtin_amdgcn_readlane(hp_u, j);
                    unsigned s1 = __builtin_amdgcn_readlane(hp_u, j + 1);
                    f16x2 p0 = bc16(s0), p1 = bc16(s1);
                    a0 = fdot2(wa[j],     p0, a0);
                    b0 = fdot2(wb[j],     p0, b0);
                    a1 = fdot2(wa[j + 1], p1, a1);
                    b1 = fdot2(wb[j + 1], p1, b1);
                }
                v2f xin = (wv == 0) ? x0ring[s & 3][l] : p1ring[s & 3][l];
                hf.x = gelu_fast((a0 + a1) + xin.x);
                hf.y = gelu_fast((b0 + b1) + xin.y);
                hp_u = cvt_pk_u(hf.x, hf.y);
                if (wv == 0) {
                    h0f16[s & 3][l] = hp_u;                       // feed xin1
                    if (s == SEQT - 1)
                        *reinterpret_cast<v2f*>(&out[YSZ + (size_t)b * HDIM + 2 * l]) = hf;
                } else {
                    *reinterpret_cast<v2f*>(&out[((size_t)s * BATCH + b) * HDIM + 2 * l]) = hf;
                    if (s == SEQT - 1)
                        *reinterpret_cast<v2f*>(
                            &out[YSZ + (size_t)BATCH * HDIM + (size_t)b * HDIM + 2 * l]) = hf;
                }
            }
        } else if (wv == 2) {
            // ---- xin1: u = t-3, reads packed-f16 h0 ring uniformly ----
            const int u = t - 3;
            if (u >= 0 && u <= SEQT - 1) {
                const unsigned* hsrc = h0f16[u & 3];
                float a0 = 0.f, a1 = 0.f, b0 = 0.f, b1 = 0.f;
                #pragma unroll
                for (int j = 0; j < 64; j += 4) {
                    uint4 q = *reinterpret_cast<const uint4*>(&hsrc[j]);
                    f16x2 p0 = bc16(q.x), p1 = bc16(q.y), p2 = bc16(q.z), p3 = bc16(q.w);
                    a0 = fdot2(wa[j],     p0, a0);  b0 = fdot2(wb[j],     p0, b0);
                    a1 = fdot2(wa[j + 1], p1, a1);  b1 = fdot2(wb[j + 1], p1, b1);
                    a0 = fdot2(wa[j + 2], p2, a0);  b0 = fdot2(wb[j + 2], p2, b0);
                    a1 = fdot2(wa[j + 3], p3, a1);  b1 = fdot2(wb[j + 3], p3, b1);
                }
                p1ring[u & 3][l] = (v2f){a0 + a1, b0 + b1};
            }
        } else {
            // ---- xin0: τ = t, reads staged f32 x uniformly, cvt on the fly ----
            if (t <= SEQT - 1) {
                const float* xs = xring[t & 3];
                float a0 = 0.f, a1 = 0.f, b0 = 0.f, b1 = 0.f;
                #pragma unroll
                for (int j = 0; j < 16; ++j) {
                    float4 v = reinterpret_cast<const float4*>(xs)[j];
                    f16x2 p0 = cvt_pk(v.x, v.y);
                    f16x2 p1 = cvt_pk(v.z, v.w);
                    a0 = fdot2(wa[2 * j],     p0, a0);  b0 = fdot2(wb[2 * j],     p0, b0);
                    a1 = fdot2(wa[2 * j + 1], p1, a1);  b1 = fdot2(wb[2 * j + 1], p1, b1);
                }
                x0ring[t & 3][l] = (v2f){a0 + a1, b0 + b1};
                if (t + 2 <= SEQT - 1) {
                    xring[(t + 2) & 3][l] = xA;                   // issued 3 iters ago
                    xA = xB; xB = xC;
                    int tn = t + 5; if (tn > SEQT - 1) tn = SEQT - 1;
                    xC = seq[(size_t)tn * BATCH * INDIM + (size_t)b * INDIM + l];
                }
            }
        }
        bar_lds();
    }
}

extern "C" void kernel_launch(void* const* d_in, const int* in_sizes, int n_in,
                              void* d_out, int out_size, void* d_ws, size_t ws_size,
                              hipStream_t stream) {
    const float* seq  = (const float*)d_in[0];
    const float* Win0 = (const float*)d_in[1];
    const float* Wh0  = (const float*)d_in[2];
    const float* Win1 = (const float*)d_in[3];
    const float* Wh1  = (const float*)d_in[4];
    const float* h00  = (const float*)d_in[5];
    const float* h01  = (const float*)d_in[6];

    rnn_scan_kernel<<<dim3(BATCH), dim3(256), 0, stream>>>(
        seq, Win0, Wh0, Win1, Wh1, h00, h01, (float*)d_out);
}

// Round 14
// 1516.364 us; speedup vs baseline: 1.1116x; 1.1116x over previous
//
#include <hip/hip_runtime.h>
#include <math.h>

#define SEQT 2048
#define BATCH 256
#define INDIM 64
#define HDIM 128

typedef float v2f __attribute__((ext_vector_type(2)));
typedef _Float16 f16x2 __attribute__((ext_vector_type(2)));

// ---- fast branch-free erf (Abramowitz-Stegun 7.1.26, |abs err| <= 1.5e-7) ----
__device__ __forceinline__ float gelu_fast(float x) {
    const float ax = __builtin_fabsf(x);
    const float z  = ax * 0.70710678118654752f;
    const float t  = __builtin_amdgcn_rcpf(__builtin_fmaf(0.3275911f, z, 1.0f));
    float p = __builtin_fmaf(1.061405429f, t, -1.453152027f);
    p = __builtin_fmaf(p, t, 1.421413741f);
    p = __builtin_fmaf(p, t, -0.284496736f);
    p = __builtin_fmaf(p, t, 0.254829592f);
    p = p * t;
    const float e = __builtin_amdgcn_exp2f(z * z * -1.44269504088896f);
    const float erfv = __builtin_fmaf(-p, e, 1.0f);
    return __builtin_fmaf(0.5f * ax, erfv, 0.5f * x);
}

// f16 dot2 with f32 accumulate (v_dot2_f32_f16)
__device__ __forceinline__ float fdot2(f16x2 a, f16x2 b, float c) {
#if __has_builtin(__builtin_amdgcn_fdot2)
    return __builtin_amdgcn_fdot2(a, b, c, false);
#else
    asm("v_dot2_f32_f16 %0, %1, %2, %0" : "+v"(c) : "v"(a), "v"(b));
    return c;
#endif
}

__device__ __forceinline__ f16x2 bc16(unsigned u) { return __builtin_bit_cast(f16x2, u); }
__device__ __forceinline__ f16x2 cvt_pk(float x, float y) {
    return __builtin_bit_cast(f16x2, __builtin_amdgcn_cvt_pkrtz(x, y));
}
__device__ __forceinline__ unsigned cvt_pk_u(float x, float y) {
    return __builtin_bit_cast(unsigned, __builtin_amdgcn_cvt_pkrtz(x, y));
}

// LDS-only barrier (measured ≈ __syncthreads; kept for the lighter wait)
__device__ __forceinline__ void bar_lds() {
    asm volatile("s_waitcnt lgkmcnt(0)\n\ts_barrier" ::: "memory");
}

// One workgroup per batch row. 256 threads = 4 waves, 1/SIMD, 1 barrier/step.
// Each wave owns ONE FULL matvec; lane l owns outputs 2l, 2l+1 (f16 weights).
//   wv0 rec0  s=t-2: h0[s]=gelu(Wh0@h0[s-1]+xin0[s]); h via OWN-WAVE readlane
//   wv1 rec1  r=t-4: h1[r]=gelu(Wh1@h1[r-1]+xin1[r]); streams y1
//   wv2 xin1  u=t-3: Win1 @ h0[u] — DEEP-PREFETCH: all 16 ds_read_b128 into a
//        register tile first (1 latency exposure), then 128 dry fdot2
//   wv3 xin0  τ=t  : Win0 @ x[τ] — same deep-prefetch; stages x (lag-3)
// At 1 wave/SIMD there is no TLP to hide LDS latency — prefetch is manual.
__global__ __launch_bounds__(256)
void rnn_scan_kernel(
    const float* __restrict__ seq,
    const float* __restrict__ Win0, const float* __restrict__ Wh0,
    const float* __restrict__ Win1, const float* __restrict__ Wh1,
    const float* __restrict__ h00, const float* __restrict__ h01,
    float* __restrict__ out)
{
    const int b = blockIdx.x;
    const int tid = threadIdx.x;
    const int wv = tid >> 6;
    const int l = tid & 63;

    __shared__ __align__(16) unsigned h0f16[4][64];   // packed-f16 h0 ring (for xin1)
    __shared__ __align__(16) v2f p1ring[4][64];       // xin1 results (per-lane)
    __shared__ __align__(16) v2f x0ring[4][64];       // xin0 results (per-lane)
    __shared__ __align__(16) float xring[4][INDIM];   // staged x (uniform-read)

    // ---- weights: rows 2l, 2l+1 as f16 pairs; complete static per-role loads ----
    f16x2 wa[64], wb[64];
    if (wv == 0 || wv == 1) {
        const float* W = (wv == 0) ? Wh0 : Wh1;
        const float* ra = &W[(2 * l) * HDIM];
        const float* rb = &W[(2 * l + 1) * HDIM];
        #pragma unroll
        for (int i = 0; i < 32; ++i) {
            float4 a = reinterpret_cast<const float4*>(ra)[i];
            float4 q = reinterpret_cast<const float4*>(rb)[i];
            wa[2 * i]     = cvt_pk(a.x, a.y);
            wa[2 * i + 1] = cvt_pk(a.z, a.w);
            wb[2 * i]     = cvt_pk(q.x, q.y);
            wb[2 * i + 1] = cvt_pk(q.z, q.w);
        }
    } else if (wv == 2) {
        const float* ra = &Win1[(2 * l) * HDIM];
        const float* rb = &Win1[(2 * l + 1) * HDIM];
        #pragma unroll
        for (int i = 0; i < 32; ++i) {
            float4 a = reinterpret_cast<const float4*>(ra)[i];
            float4 q = reinterpret_cast<const float4*>(rb)[i];
            wa[2 * i]     = cvt_pk(a.x, a.y);
            wa[2 * i + 1] = cvt_pk(a.z, a.w);
            wb[2 * i]     = cvt_pk(q.x, q.y);
            wb[2 * i + 1] = cvt_pk(q.z, q.w);
        }
    } else {
        const float* ra = &Win0[(2 * l) * INDIM];
        const float* rb = &Win0[(2 * l + 1) * INDIM];
        #pragma unroll
        for (int i = 0; i < 16; ++i) {
            float4 a = reinterpret_cast<const float4*>(ra)[i];
            float4 q = reinterpret_cast<const float4*>(rb)[i];
            wa[2 * i]     = cvt_pk(a.x, a.y);
            wa[2 * i + 1] = cvt_pk(a.z, a.w);
            wb[2 * i]     = cvt_pk(q.x, q.y);
            wb[2 * i + 1] = cvt_pk(q.z, q.w);
        }
        #pragma unroll
        for (int i = 32; i < 64; ++i) { wa[i] = (f16x2){0, 0}; wb[i] = (f16x2){0, 0}; }
    }

    // ---- init: recurrent state packed in-register; x staging (depth 3) ----
    unsigned hp_u = 0;            // lane's packed {h[2l], h[2l+1]} (rec waves)
    v2f hf = {0.f, 0.f};
    float xA = 0.f, xB = 0.f, xC = 0.f;
    if (wv == 0) {
        hf = *reinterpret_cast<const v2f*>(&h00[2 * l]);
        hp_u = cvt_pk_u(hf.x, hf.y);
    } else if (wv == 1) {
        hf = *reinterpret_cast<const v2f*>(&h01[2 * l]);
        hp_u = cvt_pk_u(hf.x, hf.y);
    } else if (wv == 3) {
        const size_t base = (size_t)b * INDIM + l;
        xring[0][l] = seq[base];
        xring[1][l] = seq[(size_t)1 * BATCH * INDIM + base];
        xA          = seq[(size_t)2 * BATCH * INDIM + base];
        xB          = seq[(size_t)3 * BATCH * INDIM + base];
        xC          = seq[(size_t)4 * BATCH * INDIM + base];
    }
    __syncthreads();

    const size_t YSZ = (size_t)SEQT * BATCH * HDIM;

    for (int t = 0; t <= SEQT + 3; ++t) {
        if (wv == 0 || wv == 1) {
            // ---- rec: wv0 s=t-2 (h0), wv1 r=t-4 (h1) ----
            const int s = (wv == 0) ? (t - 2) : (t - 4);
            if (s >= 0 && s <= SEQT - 1) {
                // hoist the 8-B xin ds_read ABOVE the ~400-cyc dot (latency hidden)
                v2f xin = (wv == 0) ? x0ring[s & 3][l] : p1ring[s & 3][l];
                float a0 = 0.f, a1 = 0.f, b0 = 0.f, b1 = 0.f;
                #pragma unroll
                for (int j = 0; j < 64; j += 2) {
                    unsigned s0 = __builtin_amdgcn_readlane(hp_u, j);
                    unsigned s1 = __builtin_amdgcn_readlane(hp_u, j + 1);
                    f16x2 p0 = bc16(s0), p1 = bc16(s1);
                    a0 = fdot2(wa[j],     p0, a0);
                    b0 = fdot2(wb[j],     p0, b0);
                    a1 = fdot2(wa[j + 1], p1, a1);
                    b1 = fdot2(wb[j + 1], p1, b1);
                }
                hf.x = gelu_fast((a0 + a1) + xin.x);
                hf.y = gelu_fast((b0 + b1) + xin.y);
                hp_u = cvt_pk_u(hf.x, hf.y);
                if (wv == 0) {
                    h0f16[s & 3][l] = hp_u;                       // feed xin1
                    if (s == SEQT - 1)
                        *reinterpret_cast<v2f*>(&out[YSZ + (size_t)b * HDIM + 2 * l]) = hf;
                } else {
                    *reinterpret_cast<v2f*>(&out[((size_t)s * BATCH + b) * HDIM + 2 * l]) = hf;
                    if (s == SEQT - 1)
                        *reinterpret_cast<v2f*>(
                            &out[YSZ + (size_t)BATCH * HDIM + (size_t)b * HDIM + 2 * l]) = hf;
                }
            }
        } else if (wv == 2) {
            // ---- xin1: u = t-3 — deep-prefetch whole h0 tile, then dry compute ----
            const int u = t - 3;
            if (u >= 0 && u <= SEQT - 1) {
                const unsigned* hsrc = h0f16[u & 3];
                uint4 q[16];
                #pragma unroll
                for (int i = 0; i < 16; ++i)
                    q[i] = reinterpret_cast<const uint4*>(hsrc)[i];   // 16 b128, 1 wait
                float a0 = 0.f, a1 = 0.f, b0 = 0.f, b1 = 0.f;
                #pragma unroll
                for (int i = 0; i < 16; ++i) {
                    const int j = 4 * i;
                    f16x2 p0 = bc16(q[i].x), p1 = bc16(q[i].y);
                    f16x2 p2 = bc16(q[i].z), p3 = bc16(q[i].w);
                    a0 = fdot2(wa[j],     p0, a0);  b0 = fdot2(wb[j],     p0, b0);
                    a1 = fdot2(wa[j + 1], p1, a1);  b1 = fdot2(wb[j + 1], p1, b1);
                    a0 = fdot2(wa[j + 2], p2, a0);  b0 = fdot2(wb[j + 2], p2, b0);
                    a1 = fdot2(wa[j + 3], p3, a1);  b1 = fdot2(wb[j + 3], p3, b1);
                }
                p1ring[u & 3][l] = (v2f){a0 + a1, b0 + b1};
            }
        } else {
            // ---- xin0: τ = t — deep-prefetch x tile, then dry compute ----
            if (t <= SEQT - 1) {
                const float* xs = xring[t & 3];
                float4 xq[16];
                #pragma unroll
                for (int i = 0; i < 16; ++i)
                    xq[i] = reinterpret_cast<const float4*>(xs)[i];   // 16 b128, 1 wait
                float a0 = 0.f, a1 = 0.f, b0 = 0.f, b1 = 0.f;
                #pragma unroll
                for (int i = 0; i < 16; ++i) {
                    f16x2 p0 = cvt_pk(xq[i].x, xq[i].y);
                    f16x2 p1 = cvt_pk(xq[i].z, xq[i].w);
                    a0 = fdot2(wa[2 * i],     p0, a0);  b0 = fdot2(wb[2 * i],     p0, b0);
                    a1 = fdot2(wa[2 * i + 1], p1, a1);  b1 = fdot2(wb[2 * i + 1], p1, b1);
                }
                x0ring[t & 3][l] = (v2f){a0 + a1, b0 + b1};
                if (t + 2 <= SEQT - 1) {
                    xring[(t + 2) & 3][l] = xA;                   // issued 3 iters ago
                    xA = xB; xB = xC;
                    int tn = t + 5; if (tn > SEQT - 1) tn = SEQT - 1;
                    xC = seq[(size_t)tn * BATCH * INDIM + (size_t)b * INDIM + l];
                }
            }
        }
        bar_lds();
    }
}

extern "C" void kernel_launch(void* const* d_in, const int* in_sizes, int n_in,
                              void* d_out, int out_size, void* d_ws, size_t ws_size,
                              hipStream_t stream) {
    const float* seq  = (const float*)d_in[0];
    const float* Win0 = (const float*)d_in[1];
    const float* Wh0  = (const float*)d_in[2];
    const float* Win1 = (const float*)d_in[3];
    const float* Wh1  = (const float*)d_in[4];
    const float* h00  = (const float*)d_in[5];
    const float* h01  = (const float*)d_in[6];

    rnn_scan_kernel<<<dim3(BATCH), dim3(256), 0, stream>>>(
        seq, Win0, Wh0, Win1, Wh1, h00, h01, (float*)d_out);
}